// Round 18
// baseline (380.863 us; speedup 1.0000x reference)
//
#include <hip/hip_runtime.h>

// ---------------------------------------------------------------------------
// DotProductAttention: out = softmax(mask(Q K^T * scale)) @ V
//                          + (q_mult @ (kv_mult^T @ V)) / (||q_mult kv_mult^T||_F + eps)
// B=2 H=16 BH=32 L=2048 D=128, f32 in/out, bf16 MFMA internally.
// v18: TLP x1.6 — 16KB blocks (single 8KB K buffer/wave, staged MID-phase
//      after lgkmcnt(0), latency hidden under softmax+PV), launch_bounds
//      (128,4) -> 16 waves/CU. bf16 O-combine (fits dead 8KB region).
// ---------------------------------------------------------------------------

typedef __attribute__((ext_vector_type(8))) __bf16 bf16x8;
typedef __attribute__((ext_vector_type(16))) float f32x16;
typedef __attribute__((ext_vector_type(4))) unsigned int u32x4;

#define DEV static __device__ __forceinline__

constexpr int LL = 2048, DD = 128, BH = 32;
constexpr float SCALE = 0.08838834764831845f;   // 1/sqrt(128)
constexpr float SCALE2 = 0.12752736105f;        // SCALE * log2(e)
constexpr float NEGV = -1e6f;

DEV unsigned pkb(float a, float b) {  // pack two f32 -> bf16x2
  union { __bf16 h[2]; unsigned u; } x;
  x.h[0] = (__bf16)a; x.h[1] = (__bf16)b;
  return x.u;
}
DEV f32x16 mfma32(bf16x8 a, bf16x8 b, f32x16 c) {
  return __builtin_amdgcn_mfma_f32_32x32x16_bf16(a, b, c, 0, 0, 0);
}
DEV void gl16(const void* g, void* l) {
  __builtin_amdgcn_global_load_lds(
      (const __attribute__((address_space(1))) unsigned int*)g,
      (__attribute__((address_space(3))) unsigned int*)l, 16, 0, 0);
}

// ---------------------------------------------------------------------------
// mega_pre: [0,512)    k_M split-8 partials -> Mp (in d_out)
//           [512,640)  gram atomics -> Gq/Gk
//           [640,1664) prep K -> bf16 swizzled 8KB tiles (bh, kt32)
//           [1664,3712) prep V -> bf16 frag-major 8KB tiles (bh, kt32)
// K tile byte(kk,d8) = kk*256 + ((d8 ^ (kk&15))<<4)
// V tile byte(f,l)   = f*1024 + l*16
// ---------------------------------------------------------------------------
__global__ __launch_bounds__(256)
void mega_pre(const float* __restrict__ K, const float* __restrict__ V,
              const float* __restrict__ qm, const float* __restrict__ km,
              char* __restrict__ Kb, char* __restrict__ Vt,
              float* __restrict__ Gq, float* __restrict__ Gk,
              float* __restrict__ Mp) {
  __shared__ __align__(16) char smem[16384];
  const int bx = blockIdx.x, tid = threadIdx.x;

  if (bx < 512) {  // ---- k_M split-8: 256 rows of km^T @ V ----
    float (*skv)[64] = (float(*)[64])smem;           // 4KB
    float (*sv)[128] = (float(*)[128])(smem + 4096); // 8KB
    int bh = bx & 31, b = bh >> 4, kc = (bx >> 5) & 7, z = (bx >> 8) & 1;
    int l0 = kc * 256;
    int j0 = (tid & 31) * 4, i0 = (tid >> 5) * 8;
    float acc[8][4];
#pragma unroll
    for (int i = 0; i < 8; ++i)
#pragma unroll
      for (int qq = 0; qq < 4; ++qq) acc[i][qq] = 0.f;
    for (int c = 0; c < 16; ++c) {
      __syncthreads();
      {
        int rr = tid >> 4, c4 = (tid & 15) * 4;
        *(float4*)&skv[rr][c4] =
            *(const float4*)(km + (size_t)(b * LL + l0 + c * 16 + rr) * DD + z * 64 + c4);
#pragma unroll
        for (int x = 0; x < 2; ++x) {
          int id2 = x * 256 + tid;
          int r2 = id2 >> 5, c42 = (id2 & 31) * 4;
          *(float4*)&sv[r2][c42] =
              *(const float4*)(V + (size_t)(bh * LL + l0 + c * 16 + r2) * DD + c42);
        }
      }
      __syncthreads();
#pragma unroll
      for (int ll = 0; ll < 16; ++ll) {
        float4 a = *(const float4*)&sv[ll][j0];
        float4 k0 = *(const float4*)&skv[ll][i0];
        float4 k1 = *(const float4*)&skv[ll][i0 + 4];
        float kk[8] = {k0.x, k0.y, k0.z, k0.w, k1.x, k1.y, k1.z, k1.w};
#pragma unroll
        for (int ii = 0; ii < 8; ++ii) {
          acc[ii][0] += kk[ii] * a.x;
          acc[ii][1] += kk[ii] * a.y;
          acc[ii][2] += kk[ii] * a.z;
          acc[ii][3] += kk[ii] * a.w;
        }
      }
    }
    float* dst = Mp + (((size_t)bh * 8 + kc) << 14) + (size_t)(z * 64 + i0) * 128 + j0;
#pragma unroll
    for (int ii = 0; ii < 8; ++ii)
      *(float4*)(dst + (size_t)ii * 128) = *(float4*)&acc[ii][0];

  } else if (bx < 640) {  // ---- gram ----
    float (*s)[128] = (float(*)[128])smem;  // 16KB
    int g = bx - 512;
    int ib = g & 7, lc = (g >> 3) & 3, wb = g >> 5;
    int which = wb >> 1, b = wb & 1;
    const float* A = (which ? km : qm) + (size_t)b * LL * DD;
    float* G = (which ? Gk : Gq) + (size_t)b * DD * DD;
    int i0 = ib * 16 + (tid >> 7) * 8, j = tid & 127;
    int l0 = lc * 512;
    float acc[8];
#pragma unroll
    for (int i = 0; i < 8; ++i) acc[i] = 0.f;
    for (int ch = 0; ch < 16; ++ch) {
      __syncthreads();
#pragma unroll
      for (int i = 0; i < 4; ++i) {
        int c = i * 256 + tid;
        int row = c >> 5, c4 = (c & 31) * 4;
        *(float4*)&s[row][c4] =
            *(const float4*)(A + (size_t)(l0 + ch * 32 + row) * DD + c4);
      }
      __syncthreads();
#pragma unroll
      for (int ll = 0; ll < 32; ++ll) {
        float aj = s[ll][j];
#pragma unroll
        for (int ii = 0; ii < 8; ++ii) acc[ii] += s[ll][i0 + ii] * aj;
      }
    }
#pragma unroll
    for (int ii = 0; ii < 8; ++ii)
      atomicAdd(&G[(size_t)(i0 + ii) * DD + j], acc[ii]);

  } else if (bx < 1664) {  // ---- prep K ----
    int pk = bx - 640;
#pragma unroll
    for (int i = 0; i < 4; ++i) {
      int cid = i * 262144 + pk * 256 + tid;
      int h = cid >> 15, k = (cid >> 4) & 2047, c = cid & 15;
      const float* p = K + ((size_t)h * LL + k) * DD + c * 8;
      float4 x0 = *(const float4*)p, x1 = *(const float4*)(p + 4);
      u32x4 v;
      v.x = pkb(x0.x, x0.y); v.y = pkb(x0.z, x0.w);
      v.z = pkb(x1.x, x1.y); v.w = pkb(x1.z, x1.w);
      char* dst = Kb + (((size_t)h * 64 + (k >> 5)) << 13) + ((k & 31) << 8) +
                  ((c ^ (k & 15)) << 4);
      *(u32x4*)dst = v;
    }

  } else {  // ---- prep V (frag-major) ----
    float (*sV)[128] = (float(*)[128])smem;  // 16KB (32 rows)
    int pv = bx - 1664;
    int h = pv >> 6, kt = pv & 63;
    const float* src = V + ((size_t)h * LL + kt * 32) * DD;
#pragma unroll
    for (int i = 0; i < 4; ++i) {
      int c = i * 256 + tid;
      int row = c >> 5, c4 = (c & 31) * 4;
      *(float4*)&sV[row][c4] = *(const float4*)(src + (size_t)row * DD + c4);
    }
    __syncthreads();
    char* dstb = Vt + (((size_t)h * 64 + kt) << 13);
#pragma unroll
    for (int i = 0; i < 2; ++i) {
      int cid = i * 256 + tid;
      int f = cid >> 6, l = cid & 63;
      int d = (f >> 1) * 32 + (l & 31);
      int k0 = ((f & 1) * 2 + (l >> 5)) * 8;
      u32x4 v;
      v.x = pkb(sV[k0 + 0][d], sV[k0 + 1][d]);
      v.y = pkb(sV[k0 + 2][d], sV[k0 + 3][d]);
      v.z = pkb(sV[k0 + 4][d], sV[k0 + 5][d]);
      v.w = pkb(sV[k0 + 6][d], sV[k0 + 7][d]);
      *(u32x4*)(dstb + f * 1024 + l * 16) = v;
    }
  }
}

// ---------------------------------------------------------------------------
// k_post: bx<2 -> fro[b]; bx>=2 -> reduce 8 Mp partials, write bf16 M^T
// M^T tile per bh (32KB): byte(d,k) = d*256 + (((k>>3) ^ (d&15))<<4) + (k&7)*2
// ---------------------------------------------------------------------------
__global__ __launch_bounds__(256)
void k_post(const float* __restrict__ Gq, const float* __restrict__ Gk,
            float* __restrict__ fro, const float* __restrict__ Mp,
            char* __restrict__ MT) {
  int bx = blockIdx.x, tid = threadIdx.x;
  if (bx < 2) {
    int b = bx;
    const float* gq = Gq + (size_t)b * DD * DD;
    const float* gk = Gk + (size_t)b * DD * DD;
    float acc = 0.f;
    for (int i = tid; i < DD * DD; i += 256) acc += gq[i] * gk[i];
#pragma unroll
    for (int m = 32; m; m >>= 1) acc += __shfl_xor(acc, m);
    __shared__ float sbuf[4];
    if ((tid & 63) == 0) sbuf[tid >> 6] = acc;
    __syncthreads();
    if (tid == 0) fro[b] = sqrtf(sbuf[0] + sbuf[1] + sbuf[2] + sbuf[3]);
  } else {
    int g = bx - 2;
    int bh = g >> 2, kq = (g & 3) * 32;
    int k = kq + (tid >> 3), d0 = (tid & 7) * 16;
    float acc[16];
#pragma unroll
    for (int i = 0; i < 16; ++i) acc[i] = 0.f;
#pragma unroll
    for (int s = 0; s < 8; ++s) {
      const float* p = Mp + (((size_t)bh * 8 + s) << 14) + (size_t)k * 128 + d0;
#pragma unroll
      for (int i = 0; i < 4; ++i) {
        float4 v = *(const float4*)(p + i * 4);
        acc[4 * i + 0] += v.x; acc[4 * i + 1] += v.y;
        acc[4 * i + 2] += v.z; acc[4 * i + 3] += v.w;
      }
    }
    char* dst = MT + (size_t)bh * 32768;
#pragma unroll
    for (int j = 0; j < 16; ++j) {
      int d = d0 + j;
      union { __bf16 h; unsigned short u; } cv;
      cv.h = (__bf16)acc[j];
      *(unsigned short*)(dst + d * 256 + (((k >> 3) ^ (d & 15)) << 4) + (k & 7) * 2) = cv.u;
    }
  }
}

// ---------------------------------------------------------------------------
// k_flash2: grid (64 qt, 32 bh) (qt-major -> L2 locality), 128 threads
// (2 waves). Wave w handles KV tiles t = w, w+2, ... Single 8KB K buffer per
// wave; K(t+2)+V(t+2) issued MID-phase after lgkmcnt(0) (QK^T ds_reads
// retired), latency hides under softmax+PV; vmcnt(0) at phase start waits
// exactly the own 16 loads. V reg double-buffered. No-max softmax via exp2;
// partials combine by ADDITION (bf16 O pack into wave1's dead K buffer).
// LDS 16KB -> VGPR-capped occupancy: launch_bounds(128,4) -> 16 waves/CU.
// ---------------------------------------------------------------------------
__global__ __launch_bounds__(128, 4)
void k_flash2(const char* __restrict__ KbG, const char* __restrict__ VtG,
              const char* __restrict__ MT, const float* __restrict__ fro,
              const float* __restrict__ Qf, const float* __restrict__ qmf,
              const int* __restrict__ vl, float* __restrict__ out) {
  __shared__ __align__(16) char lds[16384];  // 2 waves x 8KB single K buffer

  const int qt = blockIdx.x, bh = blockIdx.y, b = bh >> 4;
  const int tid = threadIdx.x, w = tid >> 6, lane = tid & 63;
  const int r32 = lane & 31, hi = lane >> 5;
  const int vlen = vl[bh];
  const size_t base = (size_t)bh * LL * DD;
  const int q = qt * 32 + r32;
  char* ldsW = lds + w * 8192;

  // Q fragments (B-operand: col=q, k=ks*16+hi*8+j), pre-scaled by scale*log2e
  bf16x8 qfr[8];
#pragma unroll
  for (int ks = 0; ks < 8; ++ks) {
    const float* p = Qf + base + (size_t)q * DD + ks * 16 + hi * 8;
    float4 x0 = *(const float4*)p, x1 = *(const float4*)(p + 4);
    union { unsigned u[4]; bf16x8 v; } u;
    u.u[0] = pkb(x0.x * SCALE2, x0.y * SCALE2);
    u.u[1] = pkb(x0.z * SCALE2, x0.w * SCALE2);
    u.u[2] = pkb(x1.x * SCALE2, x1.y * SCALE2);
    u.u[3] = pkb(x1.z * SCALE2, x1.w * SCALE2);
    qfr[ks] = u.v;
  }

  f32x16 o[4];
#pragma unroll
  for (int dt = 0; dt < 4; ++dt)
#pragma unroll
    for (int e = 0; e < 16; ++e) o[dt][e] = 0.f;
  float lrun = 0.f;

  int nt = (vlen == 0) ? 64 : ((vlen + 31) >> 5);
  const float mskv = (vlen == 0) ? 0.f : NEGV;  // exp2(0)=1 -> uniform ref path

  const char* kb = KbG + (((size_t)bh * 64) << 13);
  const char* vb = VtG + (((size_t)bh * 64) << 13);

  auto stageK = [&](int t) {
    const char* gk = kb + ((size_t)t << 13) + lane * 16;
    char* lk = ldsW + lane * 16;
#pragma unroll
    for (int i = 0; i < 8; ++i) gl16(gk + i * 1024, lk + i * 1024);
  };
  auto loadV = [&](int t, u32x4* vr) {
    const char* gv = vb + ((size_t)t << 13) + lane * 16;
#pragma unroll
    for (int f = 0; f < 8; ++f)
      vr[f] = *(const u32x4*)(gv + f * 1024);  // fully coalesced 1KB/instr
  };

  // one phase for tile t: wait own loads; QK^T from ldsW; after ds_reads
  // retire, issue K(t+2)/V(t+2); softmax+PV on vcur.
  auto phase = [&](const u32x4* vcur, u32x4* vnext, int t) {
    asm volatile("s_waitcnt vmcnt(0)" ::: "memory");  // own K(t)+V(t) arrived
    __builtin_amdgcn_sched_barrier(0);
    f32x16 s0;
#pragma unroll
    for (int e = 0; e < 16; ++e) s0[e] = 0.f;
    __builtin_amdgcn_s_setprio(1);
#pragma unroll
    for (int ks = 0; ks < 8; ++ks) {
      bf16x8 a0 = *(const bf16x8*)(ldsW + r32 * 256 + (((2 * ks + hi) ^ (r32 & 15)) << 4));
      s0 = mfma32(a0, qfr[ks], s0);
    }
    __builtin_amdgcn_s_setprio(0);
    asm volatile("s_waitcnt lgkmcnt(0)" ::: "memory");  // ds_reads retired
    __builtin_amdgcn_sched_barrier(0);
    if (t + 2 < nt) {                 // mid-phase prefetch into freed buffer
      stageK(t + 2);
      loadV(t + 2, vnext);
    }

    int kbase = t * 32;
    if (kbase + 32 > vlen) {
#pragma unroll
      for (int e = 0; e < 16; ++e) {
        int k0 = kbase + (e & 3) + 8 * (e >> 2) + 4 * hi;
        if (k0 >= vlen) s0[e] = mskv;
      }
    }
    // no-max softmax numerator: p = exp2(s*scale*log2e); masked -> 0 exactly
#pragma unroll
    for (int e = 0; e < 16; ++e) s0[e] = exp2f(s0[e]);
    f32x16 sm = s0;
#pragma unroll
    for (int st = 8; st; st >>= 1)
#pragma unroll
      for (int e = 0; e < st; ++e) sm[e] += sm[e + st];
    lrun += sm[0];

    // pack P -> bf16 B-frags (exchange halves via shfl_xor 32)
    bf16x8 PA[2];
#pragma unroll
    for (int ks = 0; ks < 2; ++ks) {
      int bb = ks * 8;
      unsigned x1 = pkb(s0[bb + 0], s0[bb + 1]);
      unsigned x2 = pkb(s0[bb + 2], s0[bb + 3]);
      unsigned y1 = pkb(s0[bb + 4], s0[bb + 5]);
      unsigned y2 = pkb(s0[bb + 6], s0[bb + 7]);
      unsigned sx1 = __shfl_xor(x1, 32), sx2 = __shfl_xor(x2, 32);
      unsigned sy1 = __shfl_xor(y1, 32), sy2 = __shfl_xor(y2, 32);
      union { unsigned u[4]; bf16x8 v; } pu;
      pu.u[0] = hi ? sy1 : x1;
      pu.u[1] = hi ? sy2 : x2;
      pu.u[2] = hi ? y1 : sx1;
      pu.u[3] = hi ? y2 : sx2;
      PA[ks] = pu.v;
    }
    __builtin_amdgcn_s_setprio(1);
#pragma unroll
    for (int dt = 0; dt < 4; ++dt)
#pragma unroll
      for (int ks = 0; ks < 2; ++ks) {
        union { u32x4 w; bf16x8 v; } cv;
        cv.w = vcur[dt * 2 + ks];
        o[dt] = mfma32(cv.v, PA[ks], o[dt]);
      }
    __builtin_amdgcn_s_setprio(0);
  };

  // ---- main loop: this wave's tiles are w, w+2, ... ----
  {
    u32x4 vA[8], vB[8];
    int t = w;
    if (t < nt) {
      stageK(t);
      loadV(t, vA);
      while (true) {
        phase(vA, vB, t);
        t += 2; if (t >= nt) break;
        phase(vB, vA, t);
        t += 2; if (t >= nt) break;
      }
    }
  }

  // ---- combine: wave1 packs O to bf16 into its own dead 8KB K buffer;
  //      barrier; wave1 writes l into wave0's dead buffer; barrier; wave0
  //      unpacks+adds, normalizes, runs fused MT epilogue, stores.
  float ltw = lrun + __shfl_xor(lrun, 32);
  unsigned* osh = (unsigned*)(lds + 8192);
  float* lshare = (float*)lds;
  if (w == 1) {
#pragma unroll
    for (int dt = 0; dt < 4; ++dt)
#pragma unroll
      for (int e2 = 0; e2 < 8; ++e2)
        osh[(dt * 8 + e2) * 64 + lane] = pkb(o[dt][2 * e2], o[dt][2 * e2 + 1]);
  }
  __syncthreads();
  if (w == 1) {
    if (hi == 0) lshare[r32] = ltw;
  }
  __syncthreads();
  if (w == 1) return;

  float lt = ltw + lshare[r32];
  float inv = 1.f / lt;
#pragma unroll
  for (int dt = 0; dt < 4; ++dt)
#pragma unroll
    for (int e2 = 0; e2 < 8; ++e2) {
      union { unsigned u; __bf16 h[2]; } cv;
      cv.u = osh[(dt * 8 + e2) * 64 + lane];
      o[dt][2 * e2]     = (o[dt][2 * e2]     + (float)cv.h[0]) * inv;
      o[dt][2 * e2 + 1] = (o[dt][2 * e2 + 1] + (float)cv.h[1]) * inv;
    }

  // ---- fused mult term ----
  {
    float invf = 1.f / (fro[b] + 1e-5f);
    bf16x8 qb[8];
#pragma unroll
    for (int ks = 0; ks < 8; ++ks) {
      const float* p = qmf + ((size_t)b * LL + q) * DD + ks * 16 + hi * 8;
      float4 x0 = *(const float4*)p, x1 = *(const float4*)(p + 4);
      union { unsigned u[4]; bf16x8 v; } u;
      u.u[0] = pkb(x0.x * invf, x0.y * invf);
      u.u[1] = pkb(x0.z * invf, x0.w * invf);
      u.u[2] = pkb(x1.x * invf, x1.y * invf);
      u.u[3] = pkb(x1.z * invf, x1.w * invf);
      qb[ks] = u.v;
    }
    const char* MTb = MT + (size_t)bh * 32768;
#pragma unroll
    for (int kc = 0; kc < 8; ++kc)
#pragma unroll
      for (int dt = 0; dt < 4; ++dt) {
        bf16x8 av = *(const bf16x8*)(MTb + (dt * 32 + r32) * 256 +
                                     (((2 * kc + hi) ^ (r32 & 15)) << 4));
        o[dt] = mfma32(av, qb[kc], o[dt]);
      }
  }

  float* op = out + base + (size_t)q * DD;
#pragma unroll
  for (int dt = 0; dt < 4; ++dt)
#pragma unroll
    for (int rq = 0; rq < 4; ++rq) {
      float4 v;
      v.x = o[dt][4 * rq + 0];
      v.y = o[dt][4 * rq + 1];
      v.z = o[dt][4 * rq + 2];
      v.w = o[dt][4 * rq + 3];
      *(float4*)(op + dt * 32 + rq * 8 + hi * 4) = v;
    }
}

// ---------------------------------------------------------------------------
// fallback flash (small ws): 2-wave blocks, stage f32 inline, attn only.
// ---------------------------------------------------------------------------
__global__ __launch_bounds__(128, 2)
void k_flashF(const float* __restrict__ Qf, const float* __restrict__ Kf,
              const float* __restrict__ Vf, const int* __restrict__ vl,
              float* __restrict__ out) {
  __shared__ __align__(16) char lds[16384];
  const int qt = blockIdx.x, bh = blockIdx.y;
  const int tid = threadIdx.x, w = tid >> 6, lane = tid & 63;
  const int r32 = lane & 31, hi = lane >> 5;
  const int vlen = vl[bh];
  const size_t base = (size_t)bh * LL * DD;
  const int q = qt * 64 + w * 32 + r32;

  bf16x8 qfr[8];
#pragma unroll
  for (int ks = 0; ks < 8; ++ks) {
    const float* p = Qf + base + (size_t)q * DD + ks * 16 + hi * 8;
    float4 x0 = *(const float4*)p, x1 = *(const float4*)(p + 4);
    union { unsigned u[4]; bf16x8 v; } u;
    u.u[0] = pkb(x0.x * SCALE, x0.y * SCALE);
    u.u[1] = pkb(x0.z * SCALE, x0.w * SCALE);
    u.u[2] = pkb(x1.x * SCALE, x1.y * SCALE);
    u.u[3] = pkb(x1.z * SCALE, x1.w * SCALE);
    qfr[ks] = u.v;
  }

  f32x16 o[4];
#pragma unroll
  for (int dt = 0; dt < 4; ++dt)
#pragma unroll
    for (int e = 0; e < 16; ++e) o[dt][e] = 0.f;
  float mrun = -3e38f, lrun = 0.f;
  int nt = (vlen == 0) ? 64 : ((vlen + 31) >> 5);

  char* Kl = lds;
  char* Vl = lds + 8192;
  for (int t = 0; t < nt; ++t) {
    int kbase = t * 32;
    __syncthreads();
#pragma unroll
    for (int i = 0; i < 4; ++i) {
      int c = i * 128 + tid;
      int kk = c >> 4, sl = c & 15;
      const float* p = Kf + base + (size_t)(kbase + kk) * DD + sl * 8;
      float4 x0 = *(const float4*)p, x1 = *(const float4*)(p + 4);
      u32x4 v;
      v.x = pkb(x0.x, x0.y); v.y = pkb(x0.z, x0.w);
      v.z = pkb(x1.x, x1.y); v.w = pkb(x1.z, x1.w);
      *(u32x4*)(Kl + (kk << 8) + ((sl ^ (kk & 15)) << 4)) = v;
    }
#pragma unroll
    for (int i = 0; i < 4; ++i) {
      int c = i * 128 + tid;
      int d = c >> 2, kk8 = c & 3;
      float t0[8];
#pragma unroll
      for (int j = 0; j < 8; ++j)
        t0[j] = Vf[base + (size_t)(kbase + kk8 * 8 + j) * DD + d];
      u32x4 v;
      v.x = pkb(t0[0], t0[1]); v.y = pkb(t0[2], t0[3]);
      v.z = pkb(t0[4], t0[5]); v.w = pkb(t0[6], t0[7]);
      *(u32x4*)(Vl + d * 64 + ((kk8 ^ ((d >> 1) & 3)) << 4)) = v;
    }
    __syncthreads();

    f32x16 s0;
#pragma unroll
    for (int e = 0; e < 16; ++e) s0[e] = 0.f;
#pragma unroll
    for (int ks = 0; ks < 8; ++ks) {
      bf16x8 a0 = *(const bf16x8*)(Kl + r32 * 256 + (((2 * ks + hi) ^ (r32 & 15)) << 4));
      s0 = mfma32(a0, qfr[ks], s0);
    }
    if (kbase + 32 > vlen) {
#pragma unroll
      for (int e = 0; e < 16; ++e) {
        int k0 = kbase + (e & 3) + 8 * (e >> 2) + 4 * hi;
        if (k0 >= vlen) s0[e] = NEGV;
      }
    }
    f32x16 mx = s0;
#pragma unroll
    for (int st = 8; st; st >>= 1)
#pragma unroll
      for (int e = 0; e < st; ++e) mx[e] = fmaxf(mx[e], mx[e + st]);
    float pm = fmaxf(mx[0], __shfl_xor(mx[0], 32));
    if (!__all(pm <= mrun + 8.f)) {
      float mn = fmaxf(mrun, pm);
      float al = __expf(mrun - mn);
      lrun *= al;
#pragma unroll
      for (int dt = 0; dt < 4; ++dt)
#pragma unroll
        for (int e = 0; e < 16; ++e) o[dt][e] *= al;
      mrun = mn;
    }
#pragma unroll
    for (int e = 0; e < 16; ++e) s0[e] = __expf(s0[e] - mrun);
    f32x16 sm = s0;
#pragma unroll
    for (int st = 8; st; st >>= 1)
#pragma unroll
      for (int e = 0; e < st; ++e) sm[e] += sm[e + st];
    lrun += sm[0];

    bf16x8 PA[2];
#pragma unroll
    for (int ks = 0; ks < 2; ++ks) {
      int bb = ks * 8;
      unsigned x1 = pkb(s0[bb + 0], s0[bb + 1]);
      unsigned x2 = pkb(s0[bb + 2], s0[bb + 3]);
      unsigned y1 = pkb(s0[bb + 4], s0[bb + 5]);
      unsigned y2 = pkb(s0[bb + 6], s0[bb + 7]);
      unsigned sx1 = __shfl_xor(x1, 32), sx2 = __shfl_xor(x2, 32);
      unsigned sy1 = __shfl_xor(y1, 32), sy2 = __shfl_xor(y2, 32);
      union { unsigned u[4]; bf16x8 v; } pu;
      pu.u[0] = hi ? sy1 : x1;
      pu.u[1] = hi ? sy2 : x2;
      pu.u[2] = hi ? y1 : sx1;
      pu.u[3] = hi ? y2 : sx2;
      PA[ks] = pu.v;
    }
#pragma unroll
    for (int dt = 0; dt < 4; ++dt)
#pragma unroll
      for (int ks = 0; ks < 2; ++ks) {
        bf16x8 av = *(const bf16x8*)(Vl + (dt * 32 + r32) * 64 +
                                     (((2 * ks + hi) ^ ((r32 >> 1) & 3)) << 4));
        o[dt] = mfma32(av, PA[ks], o[dt]);
      }
    __syncthreads();
  }

  float lt = lrun + __shfl_xor(lrun, 32);
  float inv = 1.f / lt;
  float* op = out + base + (size_t)q * DD;
#pragma unroll
  for (int dt = 0; dt < 4; ++dt)
#pragma unroll
    for (int rq = 0; rq < 4; ++rq) {
      float4 v;
      v.x = o[dt][4 * rq + 0] * inv;
      v.y = o[dt][4 * rq + 1] * inv;
      v.z = o[dt][4 * rq + 2] * inv;
      v.w = o[dt][4 * rq + 3] * inv;
      *(float4*)(op + dt * 32 + rq * 8 + hi * 4) = v;
    }
}

// ------------------- fallback-only kernels ---------------------------------
__global__ void k_gram(const float* __restrict__ qm, const float* __restrict__ km,
                       float* __restrict__ Gq, float* __restrict__ Gk) {
  int which = blockIdx.z >> 1, b = blockIdx.z & 1;
  const float* A = (which ? km : qm) + (size_t)b * LL * DD;
  float* G = (which ? Gk : Gq) + (size_t)b * DD * DD;
  int i0 = blockIdx.x * 8;
  int l0 = blockIdx.y * 512;
  __shared__ float s[32][128];
  float acc[8];
#pragma unroll
  for (int i = 0; i < 8; ++i) acc[i] = 0.f;
  for (int ch = 0; ch < 16; ++ch) {
    __syncthreads();
    for (int rr = 0; rr < 32; ++rr)
      s[rr][threadIdx.x] = A[(size_t)(l0 + ch * 32 + rr) * DD + threadIdx.x];
    __syncthreads();
    for (int ll = 0; ll < 32; ++ll) {
      float aj = s[ll][threadIdx.x];
#pragma unroll
      for (int ii = 0; ii < 8; ++ii) acc[ii] += s[ll][i0 + ii] * aj;
    }
  }
#pragma unroll
  for (int ii = 0; ii < 8; ++ii)
    atomicAdd(&G[(size_t)(i0 + ii) * DD + threadIdx.x], acc[ii]);
}

__global__ void k_fro(const float* __restrict__ Gq, const float* __restrict__ Gk,
                      float* __restrict__ fro) {
  int b = blockIdx.x;
  const float* gq = Gq + (size_t)b * DD * DD;
  const float* gk = Gk + (size_t)b * DD * DD;
  float acc = 0.f;
  for (int i = threadIdx.x; i < DD * DD; i += 256) acc += gq[i] * gk[i];
#pragma unroll
  for (int m = 32; m; m >>= 1) acc += __shfl_xor(acc, m);
  __shared__ float sbuf[4];
  if ((threadIdx.x & 63) == 0) sbuf[threadIdx.x >> 6] = acc;
  __syncthreads();
  if (threadIdx.x == 0) fro[b] = sqrtf(sbuf[0] + sbuf[1] + sbuf[2] + sbuf[3]);
}

__global__ void k_M_atomic(const float* __restrict__ km, const float* __restrict__ Vf,
                           float* __restrict__ M) {
  int bh = blockIdx.x, b = bh >> 4;
  int l0 = blockIdx.y * 128;
  __shared__ float skv[16][128];
  __shared__ float sv[16][128];
  int j0 = (threadIdx.x & 31) * 4;
  int i0 = (threadIdx.x >> 5) * 16;
  float acc[16][4];
#pragma unroll
  for (int i = 0; i < 16; ++i)
#pragma unroll
    for (int qq = 0; qq < 4; ++qq) acc[i][qq] = 0.f;
  for (int c = 0; c < 8; ++c) {
    __syncthreads();
    for (int x = 0; x < 8; ++x) {
      int idx = x * 256 + threadIdx.x;
      int rr = idx >> 7, cc = idx & 127;
      skv[rr][cc] = km[(size_t)(b * LL + l0 + c * 16 + rr) * DD + cc];
      sv[rr][cc] = Vf[(size_t)(bh * LL + l0 + c * 16 + rr) * DD + cc];
    }
    __syncthreads();
    for (int ll = 0; ll < 16; ++ll) {
      float a0 = sv[ll][j0], a1 = sv[ll][j0 + 1];
      float a2 = sv[ll][j0 + 2], a3 = sv[ll][j0 + 3];
#pragma unroll
      for (int ii = 0; ii < 16; ++ii) {
        float kv = skv[ll][i0 + ii];
        acc[ii][0] += kv * a0;
        acc[ii][1] += kv * a1;
        acc[ii][2] += kv * a2;
        acc[ii][3] += kv * a3;
      }
    }
  }
#pragma unroll
  for (int ii = 0; ii < 16; ++ii)
#pragma unroll
    for (int qq = 0; qq < 4; ++qq)
      atomicAdd(&M[(size_t)bh * DD * DD + (size_t)(i0 + ii) * DD + j0 + qq],
                acc[ii][qq]);
}

__global__ void k_multadd(const float* __restrict__ qm, const float* __restrict__ M,
                          const float* __restrict__ fro, float* __restrict__ out) {
  int bh = blockIdx.y, b = bh >> 4;
  int l = blockIdx.x * 128 + (threadIdx.x & 127);
  int dh = (threadIdx.x >> 7) * 64;
  float inv = 1.0f / (fro[b] + 1e-5f);
  const float* qrow = qm + ((size_t)b * LL + l) * DD;
  const float* Mb = M + (size_t)bh * DD * DD + dh;
  float acc[64];
#pragma unroll
  for (int i = 0; i < 64; ++i) acc[i] = 0.f;
  for (int k = 0; k < 128; ++k) {
    float qv = qrow[k];
    const float4* m4 = (const float4*)(Mb + (size_t)k * DD);
#pragma unroll
    for (int i = 0; i < 16; ++i) {
      float4 mm = m4[i];
      acc[4 * i + 0] += qv * mm.x;
      acc[4 * i + 1] += qv * mm.y;
      acc[4 * i + 2] += qv * mm.z;
      acc[4 * i + 3] += qv * mm.w;
    }
  }
  float* op = out + ((size_t)bh * LL + l) * DD + dh;
#pragma unroll
  for (int i = 0; i < 16; ++i) {
    float4 ov = ((float4*)op)[i];
    ov.x += acc[4 * i + 0] * inv;
    ov.y += acc[4 * i + 1] * inv;
    ov.z += acc[4 * i + 2] * inv;
    ov.w += acc[4 * i + 3] * inv;
    ((float4*)op)[i] = ov;
  }
}

// ---------------------------------------------------------------------------
extern "C" void kernel_launch(void* const* d_in, const int* in_sizes, int n_in,
                              void* d_out, int out_size, void* d_ws, size_t ws_size,
                              hipStream_t stream) {
  (void)in_sizes; (void)n_in; (void)out_size;
  const float* Q = (const float*)d_in[0];
  const float* K = (const float*)d_in[1];
  const float* V = (const float*)d_in[2];
  const float* qm = (const float*)d_in[3];
  const float* km = (const float*)d_in[4];
  const int* vl = (const int*)d_in[5];
  float* out = (float*)d_out;

  char* ws = (char*)d_ws;
  const size_t off_Gq = 0;                       // 128 KB
  const size_t off_Gk = 131072;                  // 128 KB
  const size_t off_fro = 262144;                 // 256 B
  const size_t off_MT = 294912;                  // 1 MB bf16 M^T tiles
  const size_t off_Kb = off_MT + 1048576;        // 16 MB bf16 K tiles
  const size_t szb = (size_t)BH * LL * DD * 2;
  const size_t off_Vt = off_Kb + szb;            // 16 MB bf16 V^T tiles
  const size_t off_end = off_Vt + szb;           // ~33.3 MB total
  bool fits = ws_size >= off_end;

  float* Gq = (float*)(ws + off_Gq);
  float* Gk = (float*)(ws + off_Gk);
  float* fro = (float*)(ws + off_fro);
  char* MT = ws + off_MT;

  if (fits) {
    float* Mp = (float*)d_out;  // 16 MB split-K partials live in out (dead until flash)
    hipMemsetAsync(ws, 0, off_fro + 256, stream);
    mega_pre<<<3712, 256, 0, stream>>>(K, V, qm, km, ws + off_Kb, ws + off_Vt,
                                       Gq, Gk, Mp);
    k_post<<<130, 256, 0, stream>>>(Gq, Gk, fro, Mp, MT);
    k_flash2<<<dim3(64, 32), 128, 0, stream>>>(ws + off_Kb, ws + off_Vt, MT, fro,
                                               Q, qm, vl, out);
  } else {
    float* Mw = (float*)(ws + off_MT);  // 2 MB f32 M (fallback only)
    hipMemsetAsync(ws, 0, off_MT + 2097152, stream);
    k_gram<<<dim3(16, 4, 4), 128, 0, stream>>>(qm, km, Gq, Gk);
    k_fro<<<2, 256, 0, stream>>>(Gq, Gk, fro);
    k_flashF<<<dim3(32, 32), 128, 0, stream>>>(Q, K, V, vl, out);
    k_M_atomic<<<dim3(32, 16), 256, 0, stream>>>(km, V, Mw);
    k_multadd<<<dim3(16, 32), 256, 0, stream>>>(qm, Mw, fro, out);
  }
}

// Round 19
// 158.060 us; speedup vs baseline: 2.4096x; 2.4096x over previous
//
#include <hip/hip_runtime.h>

// ---------------------------------------------------------------------------
// DotProductAttention: out = softmax(mask(Q K^T * scale)) @ V
//                          + (q_mult @ (kv_mult^T @ V)) / (||q_mult kv_mult^T||_F + eps)
// B=2 H=16 BH=32 L=2048 D=128, f32 in/out, bf16 MFMA internally.
// v19 = v15 verbatim (best measured: 158.4us): grid dim3(64,32) qt-major
//       (L2 locality + load balance), split-KV 2-wave blocks, 32KB LDS
//       (5 blocks/CU), counted-vmcnt depth-1 pipeline, no-max softmax via
//       exp2, fused mult-term epilogue. Final build.
// ---------------------------------------------------------------------------

typedef __attribute__((ext_vector_type(8))) __bf16 bf16x8;
typedef __attribute__((ext_vector_type(16))) float f32x16;
typedef __attribute__((ext_vector_type(4))) unsigned int u32x4;

#define DEV static __device__ __forceinline__

constexpr int LL = 2048, DD = 128, BH = 32;
constexpr float SCALE = 0.08838834764831845f;   // 1/sqrt(128)
constexpr float SCALE2 = 0.12752736105f;        // SCALE * log2(e)
constexpr float NEGV = -1e6f;

DEV unsigned pkb(float a, float b) {  // pack two f32 -> bf16x2
  union { __bf16 h[2]; unsigned u; } x;
  x.h[0] = (__bf16)a; x.h[1] = (__bf16)b;
  return x.u;
}
DEV f32x16 mfma32(bf16x8 a, bf16x8 b, f32x16 c) {
  return __builtin_amdgcn_mfma_f32_32x32x16_bf16(a, b, c, 0, 0, 0);
}
DEV void gl16(const void* g, void* l) {
  __builtin_amdgcn_global_load_lds(
      (const __attribute__((address_space(1))) unsigned int*)g,
      (__attribute__((address_space(3))) unsigned int*)l, 16, 0, 0);
}

// ---------------------------------------------------------------------------
// mega_pre: [0,512)    k_M split-8 partials -> Mp (in d_out)
//           [512,640)  gram atomics -> Gq/Gk
//           [640,1664) prep K -> bf16 swizzled 8KB tiles (bh, kt32)
//           [1664,3712) prep V -> bf16 frag-major 8KB tiles (bh, kt32)
// K tile byte(kk,d8) = kk*256 + ((d8 ^ (kk&15))<<4)
// V tile byte(f,l)   = f*1024 + l*16
// ---------------------------------------------------------------------------
__global__ __launch_bounds__(256)
void mega_pre(const float* __restrict__ K, const float* __restrict__ V,
              const float* __restrict__ qm, const float* __restrict__ km,
              char* __restrict__ Kb, char* __restrict__ Vt,
              float* __restrict__ Gq, float* __restrict__ Gk,
              float* __restrict__ Mp) {
  __shared__ __align__(16) char smem[16384];
  const int bx = blockIdx.x, tid = threadIdx.x;

  if (bx < 512) {  // ---- k_M split-8: 256 rows of km^T @ V ----
    float (*skv)[64] = (float(*)[64])smem;           // 4KB
    float (*sv)[128] = (float(*)[128])(smem + 4096); // 8KB
    int bh = bx & 31, b = bh >> 4, kc = (bx >> 5) & 7, z = (bx >> 8) & 1;
    int l0 = kc * 256;
    int j0 = (tid & 31) * 4, i0 = (tid >> 5) * 8;
    float acc[8][4];
#pragma unroll
    for (int i = 0; i < 8; ++i)
#pragma unroll
      for (int qq = 0; qq < 4; ++qq) acc[i][qq] = 0.f;
    for (int c = 0; c < 16; ++c) {
      __syncthreads();
      {
        int rr = tid >> 4, c4 = (tid & 15) * 4;
        *(float4*)&skv[rr][c4] =
            *(const float4*)(km + (size_t)(b * LL + l0 + c * 16 + rr) * DD + z * 64 + c4);
#pragma unroll
        for (int x = 0; x < 2; ++x) {
          int id2 = x * 256 + tid;
          int r2 = id2 >> 5, c42 = (id2 & 31) * 4;
          *(float4*)&sv[r2][c42] =
              *(const float4*)(V + (size_t)(bh * LL + l0 + c * 16 + r2) * DD + c42);
        }
      }
      __syncthreads();
#pragma unroll
      for (int ll = 0; ll < 16; ++ll) {
        float4 a = *(const float4*)&sv[ll][j0];
        float4 k0 = *(const float4*)&skv[ll][i0];
        float4 k1 = *(const float4*)&skv[ll][i0 + 4];
        float kk[8] = {k0.x, k0.y, k0.z, k0.w, k1.x, k1.y, k1.z, k1.w};
#pragma unroll
        for (int ii = 0; ii < 8; ++ii) {
          acc[ii][0] += kk[ii] * a.x;
          acc[ii][1] += kk[ii] * a.y;
          acc[ii][2] += kk[ii] * a.z;
          acc[ii][3] += kk[ii] * a.w;
        }
      }
    }
    float* dst = Mp + (((size_t)bh * 8 + kc) << 14) + (size_t)(z * 64 + i0) * 128 + j0;
#pragma unroll
    for (int ii = 0; ii < 8; ++ii)
      *(float4*)(dst + (size_t)ii * 128) = *(float4*)&acc[ii][0];

  } else if (bx < 640) {  // ---- gram ----
    float (*s)[128] = (float(*)[128])smem;  // 16KB
    int g = bx - 512;
    int ib = g & 7, lc = (g >> 3) & 3, wb = g >> 5;
    int which = wb >> 1, b = wb & 1;
    const float* A = (which ? km : qm) + (size_t)b * LL * DD;
    float* G = (which ? Gk : Gq) + (size_t)b * DD * DD;
    int i0 = ib * 16 + (tid >> 7) * 8, j = tid & 127;
    int l0 = lc * 512;
    float acc[8];
#pragma unroll
    for (int i = 0; i < 8; ++i) acc[i] = 0.f;
    for (int ch = 0; ch < 16; ++ch) {
      __syncthreads();
#pragma unroll
      for (int i = 0; i < 4; ++i) {
        int c = i * 256 + tid;
        int row = c >> 5, c4 = (c & 31) * 4;
        *(float4*)&s[row][c4] =
            *(const float4*)(A + (size_t)(l0 + ch * 32 + row) * DD + c4);
      }
      __syncthreads();
#pragma unroll
      for (int ll = 0; ll < 32; ++ll) {
        float aj = s[ll][j];
#pragma unroll
        for (int ii = 0; ii < 8; ++ii) acc[ii] += s[ll][i0 + ii] * aj;
      }
    }
#pragma unroll
    for (int ii = 0; ii < 8; ++ii)
      atomicAdd(&G[(size_t)(i0 + ii) * DD + j], acc[ii]);

  } else if (bx < 1664) {  // ---- prep K ----
    int pk = bx - 640;
#pragma unroll
    for (int i = 0; i < 4; ++i) {
      int cid = i * 262144 + pk * 256 + tid;
      int h = cid >> 15, k = (cid >> 4) & 2047, c = cid & 15;
      const float* p = K + ((size_t)h * LL + k) * DD + c * 8;
      float4 x0 = *(const float4*)p, x1 = *(const float4*)(p + 4);
      u32x4 v;
      v.x = pkb(x0.x, x0.y); v.y = pkb(x0.z, x0.w);
      v.z = pkb(x1.x, x1.y); v.w = pkb(x1.z, x1.w);
      char* dst = Kb + (((size_t)h * 64 + (k >> 5)) << 13) + ((k & 31) << 8) +
                  ((c ^ (k & 15)) << 4);
      *(u32x4*)dst = v;
    }

  } else {  // ---- prep V (frag-major) ----
    float (*sV)[128] = (float(*)[128])smem;  // 16KB (32 rows)
    int pv = bx - 1664;
    int h = pv >> 6, kt = pv & 63;
    const float* src = V + ((size_t)h * LL + kt * 32) * DD;
#pragma unroll
    for (int i = 0; i < 4; ++i) {
      int c = i * 256 + tid;
      int row = c >> 5, c4 = (c & 31) * 4;
      *(float4*)&sV[row][c4] = *(const float4*)(src + (size_t)row * DD + c4);
    }
    __syncthreads();
    char* dstb = Vt + (((size_t)h * 64 + kt) << 13);
#pragma unroll
    for (int i = 0; i < 2; ++i) {
      int cid = i * 256 + tid;
      int f = cid >> 6, l = cid & 63;
      int d = (f >> 1) * 32 + (l & 31);
      int k0 = ((f & 1) * 2 + (l >> 5)) * 8;
      u32x4 v;
      v.x = pkb(sV[k0 + 0][d], sV[k0 + 1][d]);
      v.y = pkb(sV[k0 + 2][d], sV[k0 + 3][d]);
      v.z = pkb(sV[k0 + 4][d], sV[k0 + 5][d]);
      v.w = pkb(sV[k0 + 6][d], sV[k0 + 7][d]);
      *(u32x4*)(dstb + f * 1024 + l * 16) = v;
    }
  }
}

// ---------------------------------------------------------------------------
// k_post: bx<2 -> fro[b]; bx>=2 -> reduce 8 Mp partials, write bf16 M^T
// M^T tile per bh (32KB): byte(d,k) = d*256 + (((k>>3) ^ (d&15))<<4) + (k&7)*2
// ---------------------------------------------------------------------------
__global__ __launch_bounds__(256)
void k_post(const float* __restrict__ Gq, const float* __restrict__ Gk,
            float* __restrict__ fro, const float* __restrict__ Mp,
            char* __restrict__ MT) {
  int bx = blockIdx.x, tid = threadIdx.x;
  if (bx < 2) {
    int b = bx;
    const float* gq = Gq + (size_t)b * DD * DD;
    const float* gk = Gk + (size_t)b * DD * DD;
    float acc = 0.f;
    for (int i = tid; i < DD * DD; i += 256) acc += gq[i] * gk[i];
#pragma unroll
    for (int m = 32; m; m >>= 1) acc += __shfl_xor(acc, m);
    __shared__ float sbuf[4];
    if ((tid & 63) == 0) sbuf[tid >> 6] = acc;
    __syncthreads();
    if (tid == 0) fro[b] = sqrtf(sbuf[0] + sbuf[1] + sbuf[2] + sbuf[3]);
  } else {
    int g = bx - 2;
    int bh = g >> 2, kq = (g & 3) * 32;
    int k = kq + (tid >> 3), d0 = (tid & 7) * 16;
    float acc[16];
#pragma unroll
    for (int i = 0; i < 16; ++i) acc[i] = 0.f;
#pragma unroll
    for (int s = 0; s < 8; ++s) {
      const float* p = Mp + (((size_t)bh * 8 + s) << 14) + (size_t)k * 128 + d0;
#pragma unroll
      for (int i = 0; i < 4; ++i) {
        float4 v = *(const float4*)(p + i * 4);
        acc[4 * i + 0] += v.x; acc[4 * i + 1] += v.y;
        acc[4 * i + 2] += v.z; acc[4 * i + 3] += v.w;
      }
    }
    char* dst = MT + (size_t)bh * 32768;
#pragma unroll
    for (int j = 0; j < 16; ++j) {
      int d = d0 + j;
      union { __bf16 h; unsigned short u; } cv;
      cv.h = (__bf16)acc[j];
      *(unsigned short*)(dst + d * 256 + (((k >> 3) ^ (d & 15)) << 4) + (k & 7) * 2) = cv.u;
    }
  }
}

// ---------------------------------------------------------------------------
// k_flash2: grid (64 qt, 32 bh) dim3 (qt-major linear order -> L2 locality),
// 128 threads (2 waves). Wave w handles KV tiles t = w, w+2, ... Each wave:
// own 16KB K dbuf via global_load_lds, reg-staged frag-major V, counted
// vmcnt(16), no barriers in the loop. No-max softmax via exp2 -> partials
// combine by ADDITION (two-barrier handshake in dead K regions). LDS exactly
// 32KB -> 5 blocks/CU.
// ---------------------------------------------------------------------------
__global__ __launch_bounds__(128, 2)
void k_flash2(const char* __restrict__ KbG, const char* __restrict__ VtG,
              const char* __restrict__ MT, const float* __restrict__ fro,
              const float* __restrict__ Qf, const float* __restrict__ qmf,
              const int* __restrict__ vl, float* __restrict__ out) {
  __shared__ __align__(16) char lds[32768];  // 2 x 16KB per-wave K dbuf

  const int qt = blockIdx.x, bh = blockIdx.y, b = bh >> 4;
  const int tid = threadIdx.x, w = tid >> 6, lane = tid & 63;
  const int r32 = lane & 31, hi = lane >> 5;
  const int vlen = vl[bh];
  const size_t base = (size_t)bh * LL * DD;
  const int q = qt * 32 + r32;
  char* ldsW = lds + w * 16384;

  // Q fragments (B-operand: col=q, k=ks*16+hi*8+j), pre-scaled by scale*log2e
  bf16x8 qfr[8];
#pragma unroll
  for (int ks = 0; ks < 8; ++ks) {
    const float* p = Qf + base + (size_t)q * DD + ks * 16 + hi * 8;
    float4 x0 = *(const float4*)p, x1 = *(const float4*)(p + 4);
    union { unsigned u[4]; bf16x8 v; } u;
    u.u[0] = pkb(x0.x * SCALE2, x0.y * SCALE2);
    u.u[1] = pkb(x0.z * SCALE2, x0.w * SCALE2);
    u.u[2] = pkb(x1.x * SCALE2, x1.y * SCALE2);
    u.u[3] = pkb(x1.z * SCALE2, x1.w * SCALE2);
    qfr[ks] = u.v;
  }

  f32x16 o[4];
#pragma unroll
  for (int dt = 0; dt < 4; ++dt)
#pragma unroll
    for (int e = 0; e < 16; ++e) o[dt][e] = 0.f;
  float lrun = 0.f;

  int nt = (vlen == 0) ? 64 : ((vlen + 31) >> 5);
  const float mskv = (vlen == 0) ? 0.f : NEGV;  // exp2(0)=1 -> uniform ref path

  const char* kb = KbG + (((size_t)bh * 64) << 13);
  const char* vb = VtG + (((size_t)bh * 64) << 13);

  auto stageK = [&](int t, int c2) {
    const char* gk = kb + ((size_t)t << 13) + lane * 16;
    char* lk = ldsW + c2 * 8192 + lane * 16;
#pragma unroll
    for (int i = 0; i < 8; ++i) gl16(gk + i * 1024, lk + i * 1024);
  };
  auto loadV = [&](int t, u32x4* vr) {
    const char* gv = vb + ((size_t)t << 13) + lane * 16;
#pragma unroll
    for (int f = 0; f < 8; ++f)
      vr[f] = *(const u32x4*)(gv + f * 1024);  // fully coalesced 1KB/instr
  };

  auto compute = [&](const char* Kl, const u32x4* vr, int kbase) {
    f32x16 s0;
#pragma unroll
    for (int e = 0; e < 16; ++e) s0[e] = 0.f;
    __builtin_amdgcn_s_setprio(1);
#pragma unroll
    for (int ks = 0; ks < 8; ++ks) {
      bf16x8 a0 = *(const bf16x8*)(Kl + r32 * 256 + (((2 * ks + hi) ^ (r32 & 15)) << 4));
      s0 = mfma32(a0, qfr[ks], s0);
    }
    __builtin_amdgcn_s_setprio(0);

    if (kbase + 32 > vlen) {
#pragma unroll
      for (int e = 0; e < 16; ++e) {
        int k0 = kbase + (e & 3) + 8 * (e >> 2) + 4 * hi;
        if (k0 >= vlen) s0[e] = mskv;
      }
    }
    // no-max softmax numerator: p = exp2(s*scale*log2e); masked -> 0 exactly
#pragma unroll
    for (int e = 0; e < 16; ++e) s0[e] = exp2f(s0[e]);
    f32x16 sm = s0;
#pragma unroll
    for (int st = 8; st; st >>= 1)
#pragma unroll
      for (int e = 0; e < st; ++e) sm[e] += sm[e + st];
    lrun += sm[0];

    // pack P -> bf16 B-frags (exchange halves via shfl_xor 32)
    bf16x8 PA[2];
#pragma unroll
    for (int ks = 0; ks < 2; ++ks) {
      int bb = ks * 8;
      unsigned x1 = pkb(s0[bb + 0], s0[bb + 1]);
      unsigned x2 = pkb(s0[bb + 2], s0[bb + 3]);
      unsigned y1 = pkb(s0[bb + 4], s0[bb + 5]);
      unsigned y2 = pkb(s0[bb + 6], s0[bb + 7]);
      unsigned sx1 = __shfl_xor(x1, 32), sx2 = __shfl_xor(x2, 32);
      unsigned sy1 = __shfl_xor(y1, 32), sy2 = __shfl_xor(y2, 32);
      union { unsigned u[4]; bf16x8 v; } pu;
      pu.u[0] = hi ? sy1 : x1;
      pu.u[1] = hi ? sy2 : x2;
      pu.u[2] = hi ? y1 : sx1;
      pu.u[3] = hi ? y2 : sx2;
      PA[ks] = pu.v;
    }
    __builtin_amdgcn_s_setprio(1);
#pragma unroll
    for (int dt = 0; dt < 4; ++dt)
#pragma unroll
      for (int ks = 0; ks < 2; ++ks) {
        union { u32x4 w; bf16x8 v; } cv;
        cv.w = vr[dt * 2 + ks];
        o[dt] = mfma32(cv.v, PA[ks], o[dt]);
      }
    __builtin_amdgcn_s_setprio(0);
  };

  // ---- main loop: this wave's tiles are w, w+2, ... ----
  {
    u32x4 vA[8], vB[8];
    int t = w;
    if (t < nt) {
      stageK(t, 0);
      loadV(t, vA);
      while (true) {
        if (t + 2 < nt) {
          stageK(t + 2, 1); loadV(t + 2, vB);
          asm volatile("s_waitcnt vmcnt(16)" ::: "memory");
        } else {
          asm volatile("s_waitcnt vmcnt(0)" ::: "memory");
        }
        __builtin_amdgcn_sched_barrier(0);
        compute(ldsW, vA, t * 32);
        t += 2; if (t >= nt) break;

        if (t + 2 < nt) {
          stageK(t + 2, 0); loadV(t + 2, vA);
          asm volatile("s_waitcnt vmcnt(16)" ::: "memory");
        } else {
          asm volatile("s_waitcnt vmcnt(0)" ::: "memory");
        }
        __builtin_amdgcn_sched_barrier(0);
        compute(ldsW + 8192, vB, t * 32);
        t += 2; if (t >= nt) break;
      }
    }
  }

  // ---- combine (two-barrier handshake, share space in dead K regions):
  //   wave1 -> O into its own region [16384,32768); sync;
  //   wave1 -> l into wave0's region [0,128); sync; wave0 combines.
  float ltw = lrun + __shfl_xor(lrun, 32);
  float* oshare = (float*)(lds + 16384);
  float* lshare = (float*)lds;
  if (w == 1) {
#pragma unroll
    for (int dt = 0; dt < 4; ++dt)
#pragma unroll
      for (int e = 0; e < 16; ++e)
        oshare[(dt * 16 + e) * 64 + lane] = o[dt][e];  // conflict-free layout
  }
  __syncthreads();
  if (w == 1) {
    if (hi == 0) lshare[r32] = ltw;
  }
  __syncthreads();
  if (w == 1) return;

  float lt = ltw + lshare[r32];
  float inv = 1.f / lt;
#pragma unroll
  for (int dt = 0; dt < 4; ++dt)
#pragma unroll
    for (int e = 0; e < 16; ++e)
      o[dt][e] = (o[dt][e] + oshare[(dt * 16 + e) * 64 + lane]) * inv;

  // ---- fused mult term ----
  {
    float invf = 1.f / (fro[b] + 1e-5f);
    bf16x8 qb[8];
#pragma unroll
    for (int ks = 0; ks < 8; ++ks) {
      const float* p = qmf + ((size_t)b * LL + q) * DD + ks * 16 + hi * 8;
      float4 x0 = *(const float4*)p, x1 = *(const float4*)(p + 4);
      union { unsigned u[4]; bf16x8 v; } u;
      u.u[0] = pkb(x0.x * invf, x0.y * invf);
      u.u[1] = pkb(x0.z * invf, x0.w * invf);
      u.u[2] = pkb(x1.x * invf, x1.y * invf);
      u.u[3] = pkb(x1.z * invf, x1.w * invf);
      qb[ks] = u.v;
    }
    const char* MTb = MT + (size_t)bh * 32768;
#pragma unroll
    for (int kc = 0; kc < 8; ++kc)
#pragma unroll
      for (int dt = 0; dt < 4; ++dt) {
        bf16x8 av = *(const bf16x8*)(MTb + (dt * 32 + r32) * 256 +
                                     (((2 * kc + hi) ^ (r32 & 15)) << 4));
        o[dt] = mfma32(av, qb[kc], o[dt]);
      }
  }

  float* op = out + base + (size_t)q * DD;
#pragma unroll
  for (int dt = 0; dt < 4; ++dt)
#pragma unroll
    for (int rq = 0; rq < 4; ++rq) {
      float4 v;
      v.x = o[dt][4 * rq + 0];
      v.y = o[dt][4 * rq + 1];
      v.z = o[dt][4 * rq + 2];
      v.w = o[dt][4 * rq + 3];
      *(float4*)(op + dt * 32 + rq * 8 + hi * 4) = v;
    }
}

// ---------------------------------------------------------------------------
// fallback flash (small ws): 2-wave blocks, stage f32 inline, attn only.
// ---------------------------------------------------------------------------
__global__ __launch_bounds__(128, 2)
void k_flashF(const float* __restrict__ Qf, const float* __restrict__ Kf,
              const float* __restrict__ Vf, const int* __restrict__ vl,
              float* __restrict__ out) {
  __shared__ __align__(16) char lds[16384];
  const int qt = blockIdx.x, bh = blockIdx.y;
  const int tid = threadIdx.x, w = tid >> 6, lane = tid & 63;
  const int r32 = lane & 31, hi = lane >> 5;
  const int vlen = vl[bh];
  const size_t base = (size_t)bh * LL * DD;
  const int q = qt * 64 + w * 32 + r32;

  bf16x8 qfr[8];
#pragma unroll
  for (int ks = 0; ks < 8; ++ks) {
    const float* p = Qf + base + (size_t)q * DD + ks * 16 + hi * 8;
    float4 x0 = *(const float4*)p, x1 = *(const float4*)(p + 4);
    union { unsigned u[4]; bf16x8 v; } u;
    u.u[0] = pkb(x0.x * SCALE, x0.y * SCALE);
    u.u[1] = pkb(x0.z * SCALE, x0.w * SCALE);
    u.u[2] = pkb(x1.x * SCALE, x1.y * SCALE);
    u.u[3] = pkb(x1.z * SCALE, x1.w * SCALE);
    qfr[ks] = u.v;
  }

  f32x16 o[4];
#pragma unroll
  for (int dt = 0; dt < 4; ++dt)
#pragma unroll
    for (int e = 0; e < 16; ++e) o[dt][e] = 0.f;
  float mrun = -3e38f, lrun = 0.f;
  int nt = (vlen == 0) ? 64 : ((vlen + 31) >> 5);

  char* Kl = lds;
  char* Vl = lds + 8192;
  for (int t = 0; t < nt; ++t) {
    int kbase = t * 32;
    __syncthreads();
#pragma unroll
    for (int i = 0; i < 4; ++i) {
      int c = i * 128 + tid;
      int kk = c >> 4, sl = c & 15;
      const float* p = Kf + base + (size_t)(kbase + kk) * DD + sl * 8;
      float4 x0 = *(const float4*)p, x1 = *(const float4*)(p + 4);
      u32x4 v;
      v.x = pkb(x0.x, x0.y); v.y = pkb(x0.z, x0.w);
      v.z = pkb(x1.x, x1.y); v.w = pkb(x1.z, x1.w);
      *(u32x4*)(Kl + (kk << 8) + ((sl ^ (kk & 15)) << 4)) = v;
    }
#pragma unroll
    for (int i = 0; i < 4; ++i) {
      int c = i * 128 + tid;
      int d = c >> 2, kk8 = c & 3;
      float t0[8];
#pragma unroll
      for (int j = 0; j < 8; ++j)
        t0[j] = Vf[base + (size_t)(kbase + kk8 * 8 + j) * DD + d];
      u32x4 v;
      v.x = pkb(t0[0], t0[1]); v.y = pkb(t0[2], t0[3]);
      v.z = pkb(t0[4], t0[5]); v.w = pkb(t0[6], t0[7]);
      *(u32x4*)(Vl + d * 64 + ((kk8 ^ ((d >> 1) & 3)) << 4)) = v;
    }
    __syncthreads();

    f32x16 s0;
#pragma unroll
    for (int e = 0; e < 16; ++e) s0[e] = 0.f;
#pragma unroll
    for (int ks = 0; ks < 8; ++ks) {
      bf16x8 a0 = *(const bf16x8*)(Kl + r32 * 256 + (((2 * ks + hi) ^ (r32 & 15)) << 4));
      s0 = mfma32(a0, qfr[ks], s0);
    }
    if (kbase + 32 > vlen) {
#pragma unroll
      for (int e = 0; e < 16; ++e) {
        int k0 = kbase + (e & 3) + 8 * (e >> 2) + 4 * hi;
        if (k0 >= vlen) s0[e] = NEGV;
      }
    }
    f32x16 mx = s0;
#pragma unroll
    for (int st = 8; st; st >>= 1)
#pragma unroll
      for (int e = 0; e < st; ++e) mx[e] = fmaxf(mx[e], mx[e + st]);
    float pm = fmaxf(mx[0], __shfl_xor(mx[0], 32));
    if (!__all(pm <= mrun + 8.f)) {
      float mn = fmaxf(mrun, pm);
      float al = __expf(mrun - mn);
      lrun *= al;
#pragma unroll
      for (int dt = 0; dt < 4; ++dt)
#pragma unroll
        for (int e = 0; e < 16; ++e) o[dt][e] *= al;
      mrun = mn;
    }
#pragma unroll
    for (int e = 0; e < 16; ++e) s0[e] = __expf(s0[e] - mrun);
    f32x16 sm = s0;
#pragma unroll
    for (int st = 8; st; st >>= 1)
#pragma unroll
      for (int e = 0; e < st; ++e) sm[e] += sm[e + st];
    lrun += sm[0];

    bf16x8 PA[2];
#pragma unroll
    for (int ks = 0; ks < 2; ++ks) {
      int bb = ks * 8;
      unsigned x1 = pkb(s0[bb + 0], s0[bb + 1]);
      unsigned x2 = pkb(s0[bb + 2], s0[bb + 3]);
      unsigned y1 = pkb(s0[bb + 4], s0[bb + 5]);
      unsigned y2 = pkb(s0[bb + 6], s0[bb + 7]);
      unsigned sx1 = __shfl_xor(x1, 32), sx2 = __shfl_xor(x2, 32);
      unsigned sy1 = __shfl_xor(y1, 32), sy2 = __shfl_xor(y2, 32);
      union { unsigned u[4]; bf16x8 v; } pu;
      pu.u[0] = hi ? sy1 : x1;
      pu.u[1] = hi ? sy2 : x2;
      pu.u[2] = hi ? y1 : sx1;
      pu.u[3] = hi ? y2 : sx2;
      PA[ks] = pu.v;
    }
#pragma unroll
    for (int dt = 0; dt < 4; ++dt)
#pragma unroll
      for (int ks = 0; ks < 2; ++ks) {
        bf16x8 av = *(const bf16x8*)(Vl + (dt * 32 + r32) * 64 +
                                     (((2 * ks + hi) ^ ((r32 >> 1) & 3)) << 4));
        o[dt] = mfma32(av, PA[ks], o[dt]);
      }
    __syncthreads();
  }

  float lt = lrun + __shfl_xor(lrun, 32);
  float inv = 1.f / lt;
  float* op = out + base + (size_t)q * DD;
#pragma unroll
  for (int dt = 0; dt < 4; ++dt)
#pragma unroll
    for (int rq = 0; rq < 4; ++rq) {
      float4 v;
      v.x = o[dt][4 * rq + 0] * inv;
      v.y = o[dt][4 * rq + 1] * inv;
      v.z = o[dt][4 * rq + 2] * inv;
      v.w = o[dt][4 * rq + 3] * inv;
      *(float4*)(op + dt * 32 + rq * 8 + hi * 4) = v;
    }
}

// ------------------- fallback-only kernels ---------------------------------
__global__ void k_gram(const float* __restrict__ qm, const float* __restrict__ km,
                       float* __restrict__ Gq, float* __restrict__ Gk) {
  int which = blockIdx.z >> 1, b = blockIdx.z & 1;
  const float* A = (which ? km : qm) + (size_t)b * LL * DD;
  float* G = (which ? Gk : Gq) + (size_t)b * DD * DD;
  int i0 = blockIdx.x * 8;
  int l0 = blockIdx.y * 512;
  __shared__ float s[32][128];
  float acc[8];
#pragma unroll
  for (int i = 0; i < 8; ++i) acc[i] = 0.f;
  for (int ch = 0; ch < 16; ++ch) {
    __syncthreads();
    for (int rr = 0; rr < 32; ++rr)
      s[rr][threadIdx.x] = A[(size_t)(l0 + ch * 32 + rr) * DD + threadIdx.x];
    __syncthreads();
    for (int ll = 0; ll < 32; ++ll) {
      float aj = s[ll][threadIdx.x];
#pragma unroll
      for (int ii = 0; ii < 8; ++ii) acc[ii] += s[ll][i0 + ii] * aj;
    }
  }
#pragma unroll
  for (int ii = 0; ii < 8; ++ii)
    atomicAdd(&G[(size_t)(i0 + ii) * DD + threadIdx.x], acc[ii]);
}

__global__ void k_fro(const float* __restrict__ Gq, const float* __restrict__ Gk,
                      float* __restrict__ fro) {
  int b = blockIdx.x;
  const float* gq = Gq + (size_t)b * DD * DD;
  const float* gk = Gk + (size_t)b * DD * DD;
  float acc = 0.f;
  for (int i = threadIdx.x; i < DD * DD; i += 256) acc += gq[i] * gk[i];
#pragma unroll
  for (int m = 32; m; m >>= 1) acc += __shfl_xor(acc, m);
  __shared__ float sbuf[4];
  if ((threadIdx.x & 63) == 0) sbuf[threadIdx.x >> 6] = acc;
  __syncthreads();
  if (threadIdx.x == 0) fro[b] = sqrtf(sbuf[0] + sbuf[1] + sbuf[2] + sbuf[3]);
}

__global__ void k_M_atomic(const float* __restrict__ km, const float* __restrict__ Vf,
                           float* __restrict__ M) {
  int bh = blockIdx.x, b = bh >> 4;
  int l0 = blockIdx.y * 128;
  __shared__ float skv[16][128];
  __shared__ float sv[16][128];
  int j0 = (threadIdx.x & 31) * 4;
  int i0 = (threadIdx.x >> 5) * 16;
  float acc[16][4];
#pragma unroll
  for (int i = 0; i < 16; ++i)
#pragma unroll
    for (int qq = 0; qq < 4; ++qq) acc[i][qq] = 0.f;
  for (int c = 0; c < 8; ++c) {
    __syncthreads();
    for (int x = 0; x < 8; ++x) {
      int idx = x * 256 + threadIdx.x;
      int rr = idx >> 7, cc = idx & 127;
      skv[rr][cc] = km[(size_t)(b * LL + l0 + c * 16 + rr) * DD + cc];
      sv[rr][cc] = Vf[(size_t)(bh * LL + l0 + c * 16 + rr) * DD + cc];
    }
    __syncthreads();
    for (int ll = 0; ll < 16; ++ll) {
      float a0 = sv[ll][j0], a1 = sv[ll][j0 + 1];
      float a2 = sv[ll][j0 + 2], a3 = sv[ll][j0 + 3];
#pragma unroll
      for (int ii = 0; ii < 16; ++ii) {
        float kv = skv[ll][i0 + ii];
        acc[ii][0] += kv * a0;
        acc[ii][1] += kv * a1;
        acc[ii][2] += kv * a2;
        acc[ii][3] += kv * a3;
      }
    }
  }
#pragma unroll
  for (int ii = 0; ii < 16; ++ii)
#pragma unroll
    for (int qq = 0; qq < 4; ++qq)
      atomicAdd(&M[(size_t)bh * DD * DD + (size_t)(i0 + ii) * DD + j0 + qq],
                acc[ii][qq]);
}

__global__ void k_multadd(const float* __restrict__ qm, const float* __restrict__ M,
                          const float* __restrict__ fro, float* __restrict__ out) {
  int bh = blockIdx.y, b = bh >> 4;
  int l = blockIdx.x * 128 + (threadIdx.x & 127);
  int dh = (threadIdx.x >> 7) * 64;
  float inv = 1.0f / (fro[b] + 1e-5f);
  const float* qrow = qm + ((size_t)b * LL + l) * DD;
  const float* Mb = M + (size_t)bh * DD * DD + dh;
  float acc[64];
#pragma unroll
  for (int i = 0; i < 64; ++i) acc[i] = 0.f;
  for (int k = 0; k < 128; ++k) {
    float qv = qrow[k];
    const float4* m4 = (const float4*)(Mb + (size_t)k * DD);
#pragma unroll
    for (int i = 0; i < 16; ++i) {
      float4 mm = m4[i];
      acc[4 * i + 0] += qv * mm.x;
      acc[4 * i + 1] += qv * mm.y;
      acc[4 * i + 2] += qv * mm.z;
      acc[4 * i + 3] += qv * mm.w;
    }
  }
  float* op = out + ((size_t)bh * LL + l) * DD + dh;
#pragma unroll
  for (int i = 0; i < 16; ++i) {
    float4 ov = ((float4*)op)[i];
    ov.x += acc[4 * i + 0] * inv;
    ov.y += acc[4 * i + 1] * inv;
    ov.z += acc[4 * i + 2] * inv;
    ov.w += acc[4 * i + 3] * inv;
    ((float4*)op)[i] = ov;
  }
}

// ---------------------------------------------------------------------------
extern "C" void kernel_launch(void* const* d_in, const int* in_sizes, int n_in,
                              void* d_out, int out_size, void* d_ws, size_t ws_size,
                              hipStream_t stream) {
  (void)in_sizes; (void)n_in; (void)out_size;
  const float* Q = (const float*)d_in[0];
  const float* K = (const float*)d_in[1];
  const float* V = (const float*)d_in[2];
  const float* qm = (const float*)d_in[3];
  const float* km = (const float*)d_in[4];
  const int* vl = (const int*)d_in[5];
  float* out = (float*)d_out;

  char* ws = (char*)d_ws;
  const size_t off_Gq = 0;                       // 128 KB
  const size_t off_Gk = 131072;                  // 128 KB
  const size_t off_fro = 262144;                 // 256 B
  const size_t off_MT = 294912;                  // 1 MB bf16 M^T tiles
  const size_t off_Kb = off_MT + 1048576;        // 16 MB bf16 K tiles
  const size_t szb = (size_t)BH * LL * DD * 2;
  const size_t off_Vt = off_Kb + szb;            // 16 MB bf16 V^T tiles
  const size_t off_end = off_Vt + szb;           // ~33.3 MB total
  bool fits = ws_size >= off_end;

  float* Gq = (float*)(ws + off_Gq);
  float* Gk = (float*)(ws + off_Gk);
  float* fro = (float*)(ws + off_fro);
  char* MT = ws + off_MT;

  if (fits) {
    float* Mp = (float*)d_out;  // 16 MB split-K partials live in out (dead until flash)
    hipMemsetAsync(ws, 0, off_fro + 256, stream);
    mega_pre<<<3712, 256, 0, stream>>>(K, V, qm, km, ws + off_Kb, ws + off_Vt,
                                       Gq, Gk, Mp);
    k_post<<<130, 256, 0, stream>>>(Gq, Gk, fro, Mp, MT);
    k_flash2<<<dim3(64, 32), 128, 0, stream>>>(ws + off_Kb, ws + off_Vt, MT, fro,
                                               Q, qm, vl, out);
  } else {
    float* Mw = (float*)(ws + off_MT);  // 2 MB f32 M (fallback only)
    hipMemsetAsync(ws, 0, off_MT + 2097152, stream);
    k_gram<<<dim3(16, 4, 4), 128, 0, stream>>>(qm, km, Gq, Gk);
    k_fro<<<2, 256, 0, stream>>>(Gq, Gk, fro);
    k_flashF<<<dim3(32, 32), 128, 0, stream>>>(Q, K, V, vl, out);
    k_M_atomic<<<dim3(32, 16), 256, 0, stream>>>(km, V, Mw);
    k_multadd<<<dim3(16, 32), 256, 0, stream>>>(qm, Mw, fro, out);
  }
}